// Round 10
// baseline (644.400 us; speedup 1.0000x reference)
//
#include <hip/hip_runtime.h>
#include <hip/hip_bf16.h>

typedef short bf16x8 __attribute__((ext_vector_type(8)));
typedef short s16x8 __attribute__((ext_vector_type(8)));
typedef float f32x4 __attribute__((ext_vector_type(4)));
typedef unsigned short u16x4 __attribute__((ext_vector_type(4)));

#define AS1(p) (const __attribute__((address_space(1))) void*)(p)
#define AS3(p) (__attribute__((address_space(3))) void*)(p)

constexpr int IMG = 2, H = 384, W = 384, DIM = 16, HID = 192;
constexpr int HP = 386, WP = 386;     // zero-padded hidden
constexpr int KTOT = 1728;            // 9 taps * 192 ch

__device__ inline short f2bf(float v) {
    __hip_bfloat16 b = __float2bfloat16(v);
    short s; __builtin_memcpy(&s, &b, 2); return s;
}
__device__ inline float bf2f(unsigned short u) {
    return __uint_as_float((unsigned)u << 16);
}

// ---------------- K0: pack w_qkv [3][3][192][192] f32 -> B^T [n][k] bf16 ----------------
__global__ __launch_bounds__(256) void pack_wqkv(const float* __restrict__ wq,
                                                 __hip_bfloat16* __restrict__ bp) {
    int idx = blockIdx.x * 256 + threadIdx.x;
    if (idx >= HID * KTOT) return;
    int n = idx / KTOT, k = idx - n * KTOT;
    int tap = k / HID, c = k - tap * HID;
    bp[idx] = __float2bfloat16(wq[(tap * HID + c) * HID + n]);
}

// ---------------- K0b: zero the padded borders of hid ----------------
__global__ __launch_bounds__(256) void border_zero(__hip_bfloat16* __restrict__ hid) {
    int idx = blockIdx.x * 256 + threadIdx.x;
    s16x8 z = {0, 0, 0, 0, 0, 0, 0, 0};
    if (idx < 37056) {                      // top/bottom full rows: 2 img x 2 rows x 9264 v8
        int img = idx / 18528, j = idx - img * 18528;
        int r = (j / 9264) ? (HP - 1) : 0;
        int off = j % 9264;
        *(s16x8*)(hid + ((size_t)(img * HP + r) * WP) * HID + (size_t)off * 8) = z;
    } else if (idx < 74112) {               // side columns: 2 img x 386 rows x 2 cols x 24 v8
        int i = idx - 37056;
        int img = i / 18528, j = i - img * 18528;
        int row = j / 48, jj = j - row * 48;
        int c = jj / 24, off = jj - c * 24;
        *(s16x8*)(hid + ((size_t)((img * HP + row) * WP) + (size_t)c * (WP - 1)) * HID + (size_t)off * 8) = z;
    }
}

// ---------------- K1: hidden = x @ w_hidden via MFMA, LDS-bounced coalesced stores ------
__global__ __launch_bounds__(256) void hidden_mfma(const float* __restrict__ x,
                                                   const float* __restrict__ wh,
                                                   __hip_bfloat16* __restrict__ hid) {
    constexpr int CST = 200;                 // row stride (shorts); 400B breaks mod-128
    __shared__ __align__(16) short cs[4][16 * CST];
    int t = threadIdx.x, wv = t >> 6, lane = t & 63;
    int m = lane & 15, half = lane >> 4;    // half = k-granule 0..3 (k = half*8+u)
    bf16x8 bfrag[12];
#pragma unroll
    for (int nb = 0; nb < 12; ++nb) {
#pragma unroll
        for (int u = 0; u < 8; ++u) {
            int k = half * 8 + u;
            float val = (k < DIM) ? wh[k * HID + nb * 16 + m] : 0.f;
            bfrag[nb][u] = f2bf(val);
        }
    }
    int wid = blockIdx.x * 4 + wv;
    short* my = &cs[wv][0];
#pragma unroll
    for (int tt = 0; tt < 2; ++tt) {
        int tile = wid * 2 + tt;            // 16-pixel tile, 18432 total
        bf16x8 af = {};
        if (half < 2) {
            const float* xp = x + (size_t)(tile * 16 + m) * DIM + half * 8;
            f32x4 x0 = *(const f32x4*)xp;
            f32x4 x1 = *(const f32x4*)(xp + 4);
#pragma unroll
            for (int u = 0; u < 4; ++u) { af[u] = f2bf(x0[u]); af[4 + u] = f2bf(x1[u]); }
        }
        f32x4 c[12];
#pragma unroll
        for (int nb = 0; nb < 12; ++nb) {
            f32x4 zz = {0.f, 0.f, 0.f, 0.f};
            c[nb] = __builtin_amdgcn_mfma_f32_16x16x32_bf16(af, bfrag[nb], zz, 0, 0, 0);
        }
        // stage C-tile to per-wave LDS [16px][192ch] (stride 200)
        asm volatile("s_waitcnt lgkmcnt(0)" ::: "memory");   // WAR vs prev tile's reads
        __builtin_amdgcn_sched_barrier(0);
#pragma unroll
        for (int nb = 0; nb < 12; ++nb)
#pragma unroll
            for (int r = 0; r < 4; ++r)
                my[(half * 4 + r) * CST + nb * 16 + m] = f2bf(c[nb][r]);
        asm volatile("s_waitcnt lgkmcnt(0)" ::: "memory");   // wave-synchronous: writes visible
        __builtin_amdgcn_sched_barrier(0);
        // coalesced 16B stores: 16 rows x 24 chunks = 384 chunks / 64 lanes
#pragma unroll
        for (int b = 0; b < 6; ++b) {
            int cch = lane + b * 64;
            int rrow = cch / 24, woff = cch - rrow * 24;
            int pix = tile * 16 + rrow;
            int img2 = pix / (H * W), rem = pix - img2 * (H * W);
            int hh = rem / W, ww = rem - hh * W;
            s16x8 val = *(const s16x8*)(my + rrow * CST + woff * 8);
            *(s16x8*)(hid + ((size_t)(img2 * HP + hh + 1) * WP + (ww + 1)) * HID + (size_t)woff * 8) = val;
        }
    }
}

// ---------------- K2: qkv = conv3x3(hidden), implicit-GEMM bf16 MFMA ----------------
// M=294912, N=192, K=1728. BM=128, BN=192, BK=64, 27 K-tiles. Double-buffered LDS.
// 2 sub-phases per tile: {stageA(t+1) | vmcnt(4) | bar | ds kk0 | mfma | bar}
//                        {stageB(t+1) |              ds kk1 | mfma | bar}
// Counted vmcnt keeps next tile's A-loads in flight across barriers (T3/T4);
// setprio(1) around MFMA clusters (T5). Granule swizzle pos = glog ^ (row&7).
__global__ __launch_bounds__(256) void conv_qkv(const __hip_bfloat16* __restrict__ hid,
                                                const __hip_bfloat16* __restrict__ bp,
                                                __hip_bfloat16* __restrict__ qkv) {
    __shared__ __align__(16) short As[2][128 * 64];   // 2 x 16 KB
    __shared__ __align__(16) short Bs[2][192 * 64];   // 2 x 24 KB
    int nb = gridDim.x;                 // 2304, divisible by 8
    int bid = blockIdx.x;
    int swz = (bid & 7) * (nb >> 3) + (bid >> 3);   // XCD-bijective swizzle
    int tw = swz % 3, row = swz / 3;
    int img = row / H, h = row - img * H;
    int w0 = tw * 128;
    int t = threadIdx.x;
    int wv = t >> 6, lane = t & 63;
    int wr = wv >> 1, wc = wv & 1;
    f32x4 acc[4][6] = {};

    auto stageA = [&](int kt, int c) {              // 128 rows x 64 ch: 1024 slots
        int tap = kt / 3, cb3 = kt - tap * 3;
        int dy = tap / 3, dx = tap - dy * 3;
        const __hip_bfloat16* abase = hid + ((size_t)(img * HP + h + dy) * WP + (w0 + dx)) * HID + cb3 * 64;
#pragma unroll
        for (int i = 0; i < 4; ++i) {
            int s = t + i * 256;
            int p = s >> 3, pg = s & 7;
            int lg = pg ^ (p & 7);                  // inverse-swizzled source granule
            __builtin_amdgcn_global_load_lds(AS1(abase + p * HID + lg * 8),
                                             AS3(&As[c][(i * 256 + wv * 64) * 8]), 16, 0, 0);
        }
    };
    auto stageB = [&](int kt, int c) {              // 192 rows x 64 k: 1536 slots
        int tap = kt / 3, cb3 = kt - tap * 3;
        const __hip_bfloat16* bbase = bp + tap * HID + cb3 * 64;
#pragma unroll
        for (int i = 0; i < 6; ++i) {
            int s = t + i * 256;
            int n = s >> 3, pg = s & 7;
            int lg = pg ^ (n & 7);
            __builtin_amdgcn_global_load_lds(AS1(bbase + (size_t)n * KTOT + lg * 8),
                                             AS3(&Bs[c][(i * 256 + wv * 64) * 8]), 16, 0, 0);
        }
    };

    stageA(0, 0);
    stageB(0, 0);
    for (int kt = 0; kt < 27; ++kt) {
        int cur = kt & 1;
        const short* Asc = &As[cur][0];
        const short* Bsc = &Bs[cur][0];
        // ---------- phase 0 (kk = 0) ----------
        if (kt < 26) {
            stageA(kt + 1, cur ^ 1);
            asm volatile("s_waitcnt vmcnt(4)" ::: "memory");   // stage(kt) landed
        } else {
            asm volatile("s_waitcnt vmcnt(0)" ::: "memory");
        }
        __builtin_amdgcn_s_barrier();               // publish stage(kt)
        {
            bf16x8 af[4], bfr[6];
#pragma unroll
            for (int m = 0; m < 4; ++m) {
                int r = wr * 64 + m * 16 + (lane & 15);
                int pos = (lane >> 4) ^ (r & 7);               // glog = 0*4 + (lane>>4)
                af[m] = *(const bf16x8*)(Asc + r * 64 + pos * 8);
            }
#pragma unroll
            for (int n = 0; n < 6; ++n) {
                int r = wc * 96 + n * 16 + (lane & 15);
                int pos = (lane >> 4) ^ (r & 7);
                bfr[n] = *(const bf16x8*)(Bsc + r * 64 + pos * 8);
            }
            asm volatile("s_waitcnt lgkmcnt(0)" ::: "memory");
            __builtin_amdgcn_sched_barrier(0);
            __builtin_amdgcn_s_setprio(1);
#pragma unroll
            for (int m = 0; m < 4; ++m)
#pragma unroll
                for (int n = 0; n < 6; ++n)
                    acc[m][n] = __builtin_amdgcn_mfma_f32_16x16x32_bf16(af[m], bfr[n], acc[m][n], 0, 0, 0);
            __builtin_amdgcn_s_setprio(0);
        }
        __builtin_amdgcn_s_barrier();
        // ---------- phase 1 (kk = 1) ----------
        if (kt < 26) stageB(kt + 1, cur ^ 1);
        {
            bf16x8 af[4], bfr[6];
#pragma unroll
            for (int m = 0; m < 4; ++m) {
                int r = wr * 64 + m * 16 + (lane & 15);
                int pos = (4 + (lane >> 4)) ^ (r & 7);         // glog = 1*4 + (lane>>4)
                af[m] = *(const bf16x8*)(Asc + r * 64 + pos * 8);
            }
#pragma unroll
            for (int n = 0; n < 6; ++n) {
                int r = wc * 96 + n * 16 + (lane & 15);
                int pos = (4 + (lane >> 4)) ^ (r & 7);
                bfr[n] = *(const bf16x8*)(Bsc + r * 64 + pos * 8);
            }
            asm volatile("s_waitcnt lgkmcnt(0)" ::: "memory");
            __builtin_amdgcn_sched_barrier(0);
            __builtin_amdgcn_s_setprio(1);
#pragma unroll
            for (int m = 0; m < 4; ++m)
#pragma unroll
                for (int n = 0; n < 6; ++n)
                    acc[m][n] = __builtin_amdgcn_mfma_f32_16x16x32_bf16(af[m], bfr[n], acc[m][n], 0, 0, 0);
            __builtin_amdgcn_s_setprio(0);
        }
        __builtin_amdgcn_s_barrier();               // end of tile; buf[cur] reads complete
    }

    int pix0 = (img * H + h) * W + w0;
#pragma unroll
    for (int m = 0; m < 4; ++m) {
#pragma unroll
        for (int n = 0; n < 6; ++n) {
            int chn = wc * 96 + n * 16 + (lane & 15);
#pragma unroll
            for (int r4 = 0; r4 < 4; ++r4) {
                int prow = wr * 64 + m * 16 + (lane >> 4) * 4 + r4;
                qkv[(size_t)(pix0 + prow) * HID + chn] = __float2bfloat16(acc[m][n][r4]);
            }
        }
    }
}

// ---------------- K3: per-patch circular conv + LN + gate + 1x1 out conv ----------------
__global__ __launch_bounds__(256) void patch_kernel(const __hip_bfloat16* __restrict__ qkv,
                                                    const float* __restrict__ lns,
                                                    const float* __restrict__ lnb,
                                                    const float* __restrict__ wout,
                                                    float* __restrict__ out) {
    constexpr int ST = 68;                    // f32 words / ushorts per px row (16B aligned)
    __shared__ __align__(16) float smem[2 * 64 * ST];   // qs | ks ; qs reused as gs
    __shared__ __align__(16) unsigned short vsm[64 * ST];
    __shared__ float wos[64 * 16];
    __shared__ float lnSs[64], lnBs[64], meanA[64], rsigA[64];
    float* qs = smem;
    float* ks = smem + 64 * ST;

    int bid = blockIdx.x;
    int pw = bid % 48;
    int tmp = bid / 48;
    int ph = tmp % 48;
    int img = tmp / 48;
    int t = threadIdx.x, wv = t >> 6, lane = t & 63;
    int base_pix = (img * H + ph * 8) * W + pw * 8;

    // ---- stage q,k,v: ushort4 vectorized, coalesced 384B runs ----
#pragma unroll
    for (int i = 0; i < 12; ++i) {
        int idx = i * 256 + t;                // 64 px x 48 ch4-groups
        int ch4 = idx % 48, px = idx / 48;
        int pix = base_pix + (px >> 3) * W + (px & 7);
        u16x4 v4 = *(const u16x4*)((const unsigned short*)qkv + (size_t)pix * HID + ch4 * 4);
        if (ch4 < 16) {
            f32x4 f = {bf2f(v4[0]), bf2f(v4[1]), bf2f(v4[2]), bf2f(v4[3])};
            *(f32x4*)(qs + px * ST + ch4 * 4) = f;
        } else if (ch4 < 32) {
            f32x4 f = {bf2f(v4[0]), bf2f(v4[1]), bf2f(v4[2]), bf2f(v4[3])};
            *(f32x4*)(ks + px * ST + (ch4 - 16) * 4) = f;
        } else {
            *(u16x4*)(vsm + px * ST + (ch4 - 32) * 4) = v4;
        }
    }
    for (int i = t; i < 64 * 16; i += 256) wos[i] = wout[i];
    if (t < 64) { lnSs[t] = lns[t]; lnBs[t] = lnb[t]; }
    __syncthreads();

    // ---- circular conv: out[a,b] = sum_{ip,j} q[(a-ip)&7][j] * k[ip][(b-j)&7], ch = lane ----
    float acc[16];
#pragma unroll
    for (int pp = 0; pp < 16; ++pp) acc[pp] = 0.f;
#pragma unroll
    for (int ip = 0; ip < 8; ++ip) {
        float kg[8];
#pragma unroll
        for (int j = 0; j < 8; ++j) kg[j] = ks[(ip * 8 + j) * ST + lane];
        int r0 = (wv * 2 - ip) & 7;
        int r1 = (wv * 2 + 1 - ip) & 7;
        float q0[8], q1[8];
#pragma unroll
        for (int j = 0; j < 8; ++j) {
            q0[j] = qs[(r0 * 8 + j) * ST + lane];
            q1[j] = qs[(r1 * 8 + j) * ST + lane];
        }
#pragma unroll
        for (int pp = 0; pp < 16; ++pp) {
            int b = pp & 7;
#pragma unroll
            for (int j = 0; j < 8; ++j) {
                float qv = (pp < 8) ? q0[j] : q1[j];
                acc[pp] += qv * kg[(b - j) & 7];
            }
        }
    }
    __syncthreads();                          // all conv reads of qs done

    // ---- write raw conv to gs[px][ch] (reuse qs region) ----
    float* gs = qs;
#pragma unroll
    for (int pp = 0; pp < 16; ++pp) {
        int p = wv * 16 + pp;
        gs[p * ST + lane] = acc[pp];          // lanes stride-1: conflict-free
    }
    __syncthreads();

    // ---- per-pixel LN stats: 4 threads per pixel ----
    {
        int px = t >> 2, qq = t & 3;
        float s = 0.f, ss = 0.f;
#pragma unroll
        for (int u = 0; u < 16; ++u) {
            float v = gs[px * ST + qq * 16 + u];
            s += v; ss += v * v;
        }
        s  += __shfl_xor(s, 1, 64);  ss += __shfl_xor(ss, 1, 64);
        s  += __shfl_xor(s, 2, 64);  ss += __shfl_xor(ss, 2, 64);
        if (qq == 0) {
            float mean = s * (1.f / 64.f);
            float var = ss * (1.f / 64.f) - mean * mean;
            meanA[px] = mean;
            rsigA[px] = rsqrtf(var + 1e-6f);
        }
    }
    __syncthreads();

    // ---- fused LN + gate + 1x1 conv (64ch -> 16) ----
    int p = t & 63, og = t >> 6;
    float mean = meanA[p], rsig = rsigA[p];
    f32x4 o = {0.f, 0.f, 0.f, 0.f};
#pragma unroll
    for (int c4 = 0; c4 < 16; ++c4) {
        f32x4 graw = *(const f32x4*)(gs + p * ST + c4 * 4);       // b128, conflict-free
        u16x4 vv = *(const u16x4*)(vsm + p * ST + c4 * 4);        // b64, conflict-free
        f32x4 s4 = *(const f32x4*)(lnSs + c4 * 4);                // broadcast
        f32x4 b4 = *(const f32x4*)(lnBs + c4 * 4);
#pragma unroll
        for (int u = 0; u < 4; ++u) {
            int ch = c4 * 4 + u;
            float vf = bf2f((unsigned short)vv[u]);
            float g = ((graw[u] - mean) * rsig * s4[u] + b4[u]) * vf;
            f32x4 w4 = *(const f32x4*)(wos + ch * 16 + og * 4);   // broadcast
            o[0] += g * w4[0]; o[1] += g * w4[1];
            o[2] += g * w4[2]; o[3] += g * w4[3];
        }
    }
    int pix = base_pix + (p >> 3) * W + (p & 7);
    *(f32x4*)(out + (size_t)pix * 16 + og * 4) = o;
}

extern "C" void kernel_launch(void* const* d_in, const int* in_sizes, int n_in,
                              void* d_out, int out_size, void* d_ws, size_t ws_size,
                              hipStream_t stream) {
    const float* x        = (const float*)d_in[0];
    const float* w_hidden = (const float*)d_in[1];
    const float* w_qkv    = (const float*)d_in[2];
    const float* ln_scale = (const float*)d_in[3];
    const float* ln_bias  = (const float*)d_in[4];
    const float* w_out    = (const float*)d_in[5];
    float* out = (float*)d_out;

    char* wsp = (char*)d_ws;
    const size_t HID_BYTES = (size_t)IMG * HP * WP * HID * 2;   // 114,428,928
    const size_t BP_BYTES  = (size_t)HID * KTOT * 2;            // 663,552
    __hip_bfloat16* hid  = (__hip_bfloat16*)wsp;
    __hip_bfloat16* bpck = (__hip_bfloat16*)(wsp + HID_BYTES);
    __hip_bfloat16* qkv  = (__hip_bfloat16*)(wsp + HID_BYTES + BP_BYTES);

    pack_wqkv<<<(HID * KTOT + 255) / 256, 256, 0, stream>>>(w_qkv, bpck);
    border_zero<<<290, 256, 0, stream>>>(hid);
    hidden_mfma<<<2304, 256, 0, stream>>>(x, w_hidden, hid);
    conv_qkv<<<2304, 256, 0, stream>>>(hid, bpck, qkv);
    patch_kernel<<<IMG * 48 * 48, 256, 0, stream>>>(qkv, ln_scale, ln_bias, w_out, out);
}

// Round 11
// 539.523 us; speedup vs baseline: 1.1944x; 1.1944x over previous
//
#include <hip/hip_runtime.h>
#include <hip/hip_bf16.h>

typedef short bf16x8 __attribute__((ext_vector_type(8)));
typedef short s16x8 __attribute__((ext_vector_type(8)));
typedef float f32x4 __attribute__((ext_vector_type(4)));
typedef unsigned short u16x4 __attribute__((ext_vector_type(4)));

#define AS1(p) (const __attribute__((address_space(1))) void*)(p)
#define AS3(p) (__attribute__((address_space(3))) void*)(p)

constexpr int IMG = 2, H = 384, W = 384, DIM = 16, HID = 192;
constexpr int HP = 386, WP = 386;     // zero-padded hidden
constexpr int KTOT = 1728;            // 9 taps * 192 ch

__device__ inline short f2bf(float v) {
    __hip_bfloat16 b = __float2bfloat16(v);
    short s; __builtin_memcpy(&s, &b, 2); return s;
}
__device__ inline float bf2f(unsigned short u) {
    return __uint_as_float((unsigned)u << 16);
}

// ---------------- K0: pack w_qkv [3][3][192][192] f32 -> B^T [n][k] bf16 ----------------
__global__ __launch_bounds__(256) void pack_wqkv(const float* __restrict__ wq,
                                                 __hip_bfloat16* __restrict__ bp) {
    int idx = blockIdx.x * 256 + threadIdx.x;
    if (idx >= HID * KTOT) return;
    int n = idx / KTOT, k = idx - n * KTOT;
    int tap = k / HID, c = k - tap * HID;
    bp[idx] = __float2bfloat16(wq[(tap * HID + c) * HID + n]);
}

// ---------------- K0b: zero the padded borders of hid ----------------
__global__ __launch_bounds__(256) void border_zero(__hip_bfloat16* __restrict__ hid) {
    int idx = blockIdx.x * 256 + threadIdx.x;
    s16x8 z = {0, 0, 0, 0, 0, 0, 0, 0};
    if (idx < 37056) {                      // top/bottom full rows: 2 img x 2 rows x 9264 v8
        int img = idx / 18528, j = idx - img * 18528;
        int r = (j / 9264) ? (HP - 1) : 0;
        int off = j % 9264;
        *(s16x8*)(hid + ((size_t)(img * HP + r) * WP) * HID + (size_t)off * 8) = z;
    } else if (idx < 74112) {               // side columns: 2 img x 386 rows x 2 cols x 24 v8
        int i = idx - 37056;
        int img = i / 18528, j = i - img * 18528;
        int row = j / 48, jj = j - row * 48;
        int c = jj / 24, off = jj - c * 24;
        *(s16x8*)(hid + ((size_t)((img * HP + row) * WP) + (size_t)c * (WP - 1)) * HID + (size_t)off * 8) = z;
    }
}

// ---------------- K1: hidden = x @ w_hidden via MFMA, LDS-bounced coalesced stores ------
__global__ __launch_bounds__(256) void hidden_mfma(const float* __restrict__ x,
                                                   const float* __restrict__ wh,
                                                   __hip_bfloat16* __restrict__ hid) {
    constexpr int CST = 200;                 // row stride (shorts); 400B breaks mod-128
    __shared__ __align__(16) short cs[4][16 * CST];
    int t = threadIdx.x, wv = t >> 6, lane = t & 63;
    int m = lane & 15, half = lane >> 4;    // half = k-granule 0..3 (k = half*8+u)
    bf16x8 bfrag[12];
#pragma unroll
    for (int nb = 0; nb < 12; ++nb) {
#pragma unroll
        for (int u = 0; u < 8; ++u) {
            int k = half * 8 + u;
            float val = (k < DIM) ? wh[k * HID + nb * 16 + m] : 0.f;
            bfrag[nb][u] = f2bf(val);
        }
    }
    int wid = blockIdx.x * 4 + wv;
    short* my = &cs[wv][0];
#pragma unroll
    for (int tt = 0; tt < 2; ++tt) {
        int tile = wid * 2 + tt;            // 16-pixel tile, 18432 total
        bf16x8 af = {};
        if (half < 2) {
            const float* xp = x + (size_t)(tile * 16 + m) * DIM + half * 8;
            f32x4 x0 = *(const f32x4*)xp;
            f32x4 x1 = *(const f32x4*)(xp + 4);
#pragma unroll
            for (int u = 0; u < 4; ++u) { af[u] = f2bf(x0[u]); af[4 + u] = f2bf(x1[u]); }
        }
        f32x4 c[12];
#pragma unroll
        for (int nb = 0; nb < 12; ++nb) {
            f32x4 zz = {0.f, 0.f, 0.f, 0.f};
            c[nb] = __builtin_amdgcn_mfma_f32_16x16x32_bf16(af, bfrag[nb], zz, 0, 0, 0);
        }
        // stage C-tile to per-wave LDS [16px][192ch] (stride 200)
        asm volatile("s_waitcnt lgkmcnt(0)" ::: "memory");   // WAR vs prev tile's reads
        __builtin_amdgcn_sched_barrier(0);
#pragma unroll
        for (int nb = 0; nb < 12; ++nb)
#pragma unroll
            for (int r = 0; r < 4; ++r)
                my[(half * 4 + r) * CST + nb * 16 + m] = f2bf(c[nb][r]);
        asm volatile("s_waitcnt lgkmcnt(0)" ::: "memory");   // wave-synchronous: writes visible
        __builtin_amdgcn_sched_barrier(0);
        // coalesced 16B stores: 16 rows x 24 chunks = 384 chunks / 64 lanes
#pragma unroll
        for (int b = 0; b < 6; ++b) {
            int cch = lane + b * 64;
            int rrow = cch / 24, woff = cch - rrow * 24;
            int pix = tile * 16 + rrow;
            int img2 = pix / (H * W), rem = pix - img2 * (H * W);
            int hh = rem / W, ww = rem - hh * W;
            s16x8 val = *(const s16x8*)(my + rrow * CST + woff * 8);
            *(s16x8*)(hid + ((size_t)(img2 * HP + hh + 1) * WP + (ww + 1)) * HID + (size_t)woff * 8) = val;
        }
    }
}

// ---------------- K2: qkv = conv3x3(hidden), implicit-GEMM bf16 MFMA ----------------
// M=294912, N=192, K=1728. BM=128, BN=192, BK=32, 54 K-steps. Double-buffered LDS
// (40 KB total -> 4 blocks/CU). Each K-step split into 2 phases:
//  P0: stageA(kk+1) | vmcnt(2) | bar | ds af[0..3]+bfr[0..2] | lgkm0 | prio1 12 MFMA | bar
//  P1: stageB(kk+1) |                  ds bfr[3..5]          | lgkm0 | prio1 12 MFMA | bar
// Counted vmcnt keeps A(kk+1) in flight across barriers (T4); mid-barrier creates
// wave role-diversity so setprio pays (T3/T5). Granule swizzle g = (lane>>4)^((r>>1)&3).
__global__ __launch_bounds__(256) void conv_qkv(const __hip_bfloat16* __restrict__ hid,
                                                const __hip_bfloat16* __restrict__ bp,
                                                __hip_bfloat16* __restrict__ qkv) {
    __shared__ __align__(16) short As[2][128 * 32];   // 2 x 8 KB
    __shared__ __align__(16) short Bs[2][192 * 32];   // 2 x 12 KB
    int nb = gridDim.x;                 // 2304, divisible by 8
    int bid = blockIdx.x;
    int swz = (bid & 7) * (nb >> 3) + (bid >> 3);   // XCD-bijective swizzle
    int tw = swz % 3, row = swz / 3;
    int img = row / H, h = row - img * H;
    int w0 = tw * 128;
    int t = threadIdx.x;
    int wv = t >> 6, lane = t & 63;
    int wr = wv >> 1, wc = wv & 1;
    f32x4 acc[4][6] = {};

    auto stageA = [&](int kk, int c) {              // A: 128 rows x 4 granules, 2 loads/thread
        int tap = kk / 6, cb = kk - tap * 6;
        int dy = tap / 3, dx = tap - dy * 3;
        const __hip_bfloat16* abase = hid + ((size_t)(img * HP + h + dy) * WP + (w0 + dx)) * HID + cb * 32;
#pragma unroll
        for (int i = 0; i < 2; ++i) {
            int s = t + i * 256;
            int p = s >> 2, pg = s & 3;
            int lg = pg ^ ((p >> 1) & 3);           // inverse-swizzled source granule
            __builtin_amdgcn_global_load_lds(AS1(abase + p * HID + lg * 8),
                                             AS3(&As[c][(i * 256 + wv * 64) * 8]), 16, 0, 0);
        }
    };
    auto stageB = [&](int kk, int c) {              // B: 192 rows x 4 granules, 3 loads/thread
        int tap = kk / 6, cb = kk - tap * 6;
        const __hip_bfloat16* bbase = bp + tap * HID + cb * 32;
#pragma unroll
        for (int i = 0; i < 3; ++i) {
            int s = t + i * 256;
            int n = s >> 2, pg = s & 3;
            int lg = pg ^ ((n >> 1) & 3);
            __builtin_amdgcn_global_load_lds(AS1(bbase + (size_t)n * KTOT + lg * 8),
                                             AS3(&Bs[c][(i * 256 + wv * 64) * 8]), 16, 0, 0);
        }
    };

    stageA(0, 0);
    stageB(0, 0);
    for (int kk = 0; kk < 54; ++kk) {
        int cur = kk & 1;
        const short* Asc = &As[cur][0];
        const short* Bsc = &Bs[cur][0];
        bf16x8 af[4], bfr[6];
        // ---------- phase 0 ----------
        if (kk < 53) {
            stageA(kk + 1, cur ^ 1);
            asm volatile("s_waitcnt vmcnt(2)" ::: "memory");   // A(kk),B(kk) landed; A(kk+1) in flight
        } else {
            asm volatile("s_waitcnt vmcnt(0)" ::: "memory");
        }
        __builtin_amdgcn_s_barrier();               // publish stage(kk)
#pragma unroll
        for (int m = 0; m < 4; ++m) {
            int r = wr * 64 + m * 16 + (lane & 15);
            int g = (lane >> 4) ^ ((r >> 1) & 3);
            af[m] = *(const bf16x8*)(Asc + r * 32 + g * 8);
        }
#pragma unroll
        for (int n = 0; n < 3; ++n) {
            int r = wc * 96 + n * 16 + (lane & 15);
            int g = (lane >> 4) ^ ((r >> 1) & 3);
            bfr[n] = *(const bf16x8*)(Bsc + r * 32 + g * 8);
        }
        asm volatile("s_waitcnt lgkmcnt(0)" ::: "memory");
        __builtin_amdgcn_sched_barrier(0);
        __builtin_amdgcn_s_setprio(1);
#pragma unroll
        for (int m = 0; m < 4; ++m)
#pragma unroll
            for (int n = 0; n < 3; ++n)
                acc[m][n] = __builtin_amdgcn_mfma_f32_16x16x32_bf16(af[m], bfr[n], acc[m][n], 0, 0, 0);
        __builtin_amdgcn_s_setprio(0);
        __builtin_amdgcn_s_barrier();               // phase boundary (role diversity)
        // ---------- phase 1 ----------
        if (kk < 53) stageB(kk + 1, cur ^ 1);
#pragma unroll
        for (int n = 3; n < 6; ++n) {
            int r = wc * 96 + n * 16 + (lane & 15);
            int g = (lane >> 4) ^ ((r >> 1) & 3);
            bfr[n] = *(const bf16x8*)(Bsc + r * 32 + g * 8);
        }
        asm volatile("s_waitcnt lgkmcnt(0)" ::: "memory");
        __builtin_amdgcn_sched_barrier(0);
        __builtin_amdgcn_s_setprio(1);
#pragma unroll
        for (int m = 0; m < 4; ++m)
#pragma unroll
            for (int n = 3; n < 6; ++n)
                acc[m][n] = __builtin_amdgcn_mfma_f32_16x16x32_bf16(af[m], bfr[n], acc[m][n], 0, 0, 0);
        __builtin_amdgcn_s_setprio(0);
        __builtin_amdgcn_s_barrier();               // end of K-step; buf[cur] reads complete
    }

    int pix0 = (img * H + h) * W + w0;
#pragma unroll
    for (int m = 0; m < 4; ++m) {
#pragma unroll
        for (int n = 0; n < 6; ++n) {
            int chn = wc * 96 + n * 16 + (lane & 15);
#pragma unroll
            for (int r4 = 0; r4 < 4; ++r4) {
                int prow = wr * 64 + m * 16 + (lane >> 4) * 4 + r4;
                qkv[(size_t)(pix0 + prow) * HID + chn] = __float2bfloat16(acc[m][n][r4]);
            }
        }
    }
}

// ---------------- K3: per-patch circular conv + LN + gate + 1x1 out conv ----------------
__global__ __launch_bounds__(256) void patch_kernel(const __hip_bfloat16* __restrict__ qkv,
                                                    const float* __restrict__ lns,
                                                    const float* __restrict__ lnb,
                                                    const float* __restrict__ wout,
                                                    float* __restrict__ out) {
    constexpr int ST = 68;                    // f32 words / ushorts per px row (16B aligned)
    __shared__ __align__(16) float smem[2 * 64 * ST];   // qs | ks ; qs reused as gs
    __shared__ __align__(16) unsigned short vsm[64 * ST];
    __shared__ float wos[64 * 16];
    __shared__ float lnSs[64], lnBs[64], meanA[64], rsigA[64];
    float* qs = smem;
    float* ks = smem + 64 * ST;

    int bid = blockIdx.x;
    int pw = bid % 48;
    int tmp = bid / 48;
    int ph = tmp % 48;
    int img = tmp / 48;
    int t = threadIdx.x, wv = t >> 6, lane = t & 63;
    int base_pix = (img * H + ph * 8) * W + pw * 8;

    // ---- stage q,k,v: ushort4 vectorized, coalesced 384B runs ----
#pragma unroll
    for (int i = 0; i < 12; ++i) {
        int idx = i * 256 + t;                // 64 px x 48 ch4-groups
        int ch4 = idx % 48, px = idx / 48;
        int pix = base_pix + (px >> 3) * W + (px & 7);
        u16x4 v4 = *(const u16x4*)((const unsigned short*)qkv + (size_t)pix * HID + ch4 * 4);
        if (ch4 < 16) {
            f32x4 f = {bf2f(v4[0]), bf2f(v4[1]), bf2f(v4[2]), bf2f(v4[3])};
            *(f32x4*)(qs + px * ST + ch4 * 4) = f;
        } else if (ch4 < 32) {
            f32x4 f = {bf2f(v4[0]), bf2f(v4[1]), bf2f(v4[2]), bf2f(v4[3])};
            *(f32x4*)(ks + px * ST + (ch4 - 16) * 4) = f;
        } else {
            *(u16x4*)(vsm + px * ST + (ch4 - 32) * 4) = v4;
        }
    }
    for (int i = t; i < 64 * 16; i += 256) wos[i] = wout[i];
    if (t < 64) { lnSs[t] = lns[t]; lnBs[t] = lnb[t]; }
    __syncthreads();

    // ---- circular conv: out[a,b] = sum_{ip,j} q[(a-ip)&7][j] * k[ip][(b-j)&7], ch = lane ----
    float acc[16];
#pragma unroll
    for (int pp = 0; pp < 16; ++pp) acc[pp] = 0.f;
#pragma unroll
    for (int ip = 0; ip < 8; ++ip) {
        float kg[8];
#pragma unroll
        for (int j = 0; j < 8; ++j) kg[j] = ks[(ip * 8 + j) * ST + lane];
        int r0 = (wv * 2 - ip) & 7;
        int r1 = (wv * 2 + 1 - ip) & 7;
        float q0[8], q1[8];
#pragma unroll
        for (int j = 0; j < 8; ++j) {
            q0[j] = qs[(r0 * 8 + j) * ST + lane];
            q1[j] = qs[(r1 * 8 + j) * ST + lane];
        }
#pragma unroll
        for (int pp = 0; pp < 16; ++pp) {
            int b = pp & 7;
#pragma unroll
            for (int j = 0; j < 8; ++j) {
                float qv = (pp < 8) ? q0[j] : q1[j];
                acc[pp] += qv * kg[(b - j) & 7];
            }
        }
    }
    __syncthreads();                          // all conv reads of qs done

    // ---- write raw conv to gs[px][ch] (reuse qs region) ----
    float* gs = qs;
#pragma unroll
    for (int pp = 0; pp < 16; ++pp) {
        int p = wv * 16 + pp;
        gs[p * ST + lane] = acc[pp];          // lanes stride-1: conflict-free
    }
    __syncthreads();

    // ---- per-pixel LN stats: 4 threads per pixel ----
    {
        int px = t >> 2, qq = t & 3;
        float s = 0.f, ss = 0.f;
#pragma unroll
        for (int u = 0; u < 16; ++u) {
            float v = gs[px * ST + qq * 16 + u];
            s += v; ss += v * v;
        }
        s  += __shfl_xor(s, 1, 64);  ss += __shfl_xor(ss, 1, 64);
        s  += __shfl_xor(s, 2, 64);  ss += __shfl_xor(ss, 2, 64);
        if (qq == 0) {
            float mean = s * (1.f / 64.f);
            float var = ss * (1.f / 64.f) - mean * mean;
            meanA[px] = mean;
            rsigA[px] = rsqrtf(var + 1e-6f);
        }
    }
    __syncthreads();

    // ---- fused LN + gate + 1x1 conv (64ch -> 16) ----
    int p = t & 63, og = t >> 6;
    float mean = meanA[p], rsig = rsigA[p];
    f32x4 o = {0.f, 0.f, 0.f, 0.f};
#pragma unroll
    for (int c4 = 0; c4 < 16; ++c4) {
        f32x4 graw = *(const f32x4*)(gs + p * ST + c4 * 4);       // b128, conflict-free
        u16x4 vv = *(const u16x4*)(vsm + p * ST + c4 * 4);        // b64, conflict-free
        f32x4 s4 = *(const f32x4*)(lnSs + c4 * 4);                // broadcast
        f32x4 b4 = *(const f32x4*)(lnBs + c4 * 4);
#pragma unroll
        for (int u = 0; u < 4; ++u) {
            int ch = c4 * 4 + u;
            float vf = bf2f((unsigned short)vv[u]);
            float g = ((graw[u] - mean) * rsig * s4[u] + b4[u]) * vf;
            f32x4 w4 = *(const f32x4*)(wos + ch * 16 + og * 4);   // broadcast
            o[0] += g * w4[0]; o[1] += g * w4[1];
            o[2] += g * w4[2]; o[3] += g * w4[3];
        }
    }
    int pix = base_pix + (p >> 3) * W + (p & 7);
    *(f32x4*)(out + (size_t)pix * 16 + og * 4) = o;
}

extern "C" void kernel_launch(void* const* d_in, const int* in_sizes, int n_in,
                              void* d_out, int out_size, void* d_ws, size_t ws_size,
                              hipStream_t stream) {
    const float* x        = (const float*)d_in[0];
    const float* w_hidden = (const float*)d_in[1];
    const float* w_qkv    = (const float*)d_in[2];
    const float* ln_scale = (const float*)d_in[3];
    const float* ln_bias  = (const float*)d_in[4];
    const float* w_out    = (const float*)d_in[5];
    float* out = (float*)d_out;

    char* wsp = (char*)d_ws;
    const size_t HID_BYTES = (size_t)IMG * HP * WP * HID * 2;   // 114,428,928
    const size_t BP_BYTES  = (size_t)HID * KTOT * 2;            // 663,552
    __hip_bfloat16* hid  = (__hip_bfloat16*)wsp;
    __hip_bfloat16* bpck = (__hip_bfloat16*)(wsp + HID_BYTES);
    __hip_bfloat16* qkv  = (__hip_bfloat16*)(wsp + HID_BYTES + BP_BYTES);

    pack_wqkv<<<(HID * KTOT + 255) / 256, 256, 0, stream>>>(w_qkv, bpck);
    border_zero<<<290, 256, 0, stream>>>(hid);
    hidden_mfma<<<2304, 256, 0, stream>>>(x, w_hidden, hid);
    conv_qkv<<<2304, 256, 0, stream>>>(hid, bpck, qkv);
    patch_kernel<<<IMG * 48 * 48, 256, 0, stream>>>(qkv, ln_scale, ln_bias, w_out, out);
}

// Round 12
// 202.649 us; speedup vs baseline: 3.1799x; 2.6624x over previous
//
#include <hip/hip_runtime.h>
#include <hip/hip_bf16.h>

typedef short bf16x8 __attribute__((ext_vector_type(8)));
typedef short s16x8 __attribute__((ext_vector_type(8)));
typedef float f32x4 __attribute__((ext_vector_type(4)));
typedef unsigned short u16x4 __attribute__((ext_vector_type(4)));

#define AS1(p) (const __attribute__((address_space(1))) void*)(p)
#define AS3(p) (__attribute__((address_space(3))) void*)(p)

constexpr int IMG = 2, H = 384, W = 384, DIM = 16, HID = 192;
constexpr int XR = 388, XC = 386;     // padded x: rows 0..387 (386,387 zero), cols 0..385
constexpr int KP = 160;               // padded K (9 taps * 16 ch = 144, pad to 160)

__device__ inline short f2bf(float v) {
    __hip_bfloat16 b = __float2bfloat16(v);
    short s; __builtin_memcpy(&s, &b, 2); return s;
}
__device__ inline float bf2f(unsigned short u) {
    return __uint_as_float((unsigned)u << 16);
}

// ---- K0: Weff[tau][j][n] = sum_c wh[j][c] * wq[tau][c][n], packed [g][n][8] bf16 ----
// k = tau*16 + j (k<144; zeros to 160). g = k>>3, e = k&7.
__global__ __launch_bounds__(256) void weff_pack(const float* __restrict__ wh,
                                                 const float* __restrict__ wq,
                                                 __hip_bfloat16* __restrict__ wp) {
    int idx = blockIdx.x * 256 + threadIdx.x;     // 160*192 = 30720
    if (idx >= KP * HID) return;
    int n = idx % HID, k = idx / HID;
    float v = 0.f;
    if (k < 144) {
        int tau = k >> 4, j = k & 15;
        const float* whp = wh + j * HID;
        const float* wqp = wq + (size_t)tau * HID * HID + n;
#pragma unroll 4
        for (int c = 0; c < HID; ++c) v += whp[c] * wqp[(size_t)c * HID];
    }
    int g = k >> 3, e = k & 7;
    wp[((size_t)g * HID + n) * 8 + e] = __float2bfloat16(v);
}

// ---- K1: pad x -> xp[2][388][386][16] bf16 (border + rows 386/387 zero) ----
__global__ __launch_bounds__(256) void xpad(const float* __restrict__ x,
                                            __hip_bfloat16* __restrict__ xp) {
    int p = blockIdx.x * 256 + threadIdx.x;
    if (p >= IMG * XR * XC) return;
    int img = p / (XR * XC), rem = p - img * (XR * XC);
    int r = rem / XC, c = rem - r * XC;
    s16x8 lo = {0,0,0,0,0,0,0,0}, hi = {0,0,0,0,0,0,0,0};
    if (r >= 1 && r <= H && c >= 1 && c <= W) {
        const float* src = x + ((size_t)(img * H + r - 1) * W + (c - 1)) * DIM;
        f32x4 a0 = *(const f32x4*)(src), a1 = *(const f32x4*)(src + 4);
        f32x4 a2 = *(const f32x4*)(src + 8), a3 = *(const f32x4*)(src + 12);
#pragma unroll
        for (int u = 0; u < 4; ++u) {
            lo[u] = f2bf(a0[u]); lo[4 + u] = f2bf(a1[u]);
            hi[u] = f2bf(a2[u]); hi[4 + u] = f2bf(a3[u]);
        }
    }
    short* dst = (short*)xp + (size_t)p * DIM;
    *(s16x8*)dst = lo;
    *(s16x8*)(dst + 8) = hi;
}

// ---- K2: qkv = conv3x3(x @ Wh) fused as x (*) Weff. M=294912, N=192, K=144(->160) ----
// BM=128, BN=192, 4 waves (wave tile 64x96). B (Weff^T) staged to LDS once, no
// barriers in K-loop (5 unrolled steps). A read per-lane direct from L2-resident xp.
// Epilogue: LDS bounce (stride 200) -> fully coalesced 16B global stores.
__global__ __launch_bounds__(256) void conv_fused(const __hip_bfloat16* __restrict__ xp,
                                                  const __hip_bfloat16* __restrict__ wp,
                                                  __hip_bfloat16* __restrict__ qkv) {
    __shared__ __align__(16) short Bs[20 * HID * 8];   // 61,440 B; reused as C-bounce
    int nb = gridDim.x;                 // 2304, divisible by 8
    int bid = blockIdx.x;
    int swz = (bid & 7) * (nb >> 3) + (bid >> 3);      // XCD-bijective swizzle
    int tw = swz % 3, row = swz / 3;
    int img = row / H, h = row - img * H;
    int w0 = tw * 128;
    int t = threadIdx.x;
    int wv = t >> 6, lane = t & 63;
    int wr = wv >> 1, wc = wv & 1;
    int m0 = lane & 15, half = lane >> 4;

    // stage Weff^T (linear copy: source layout == LDS layout): 15 x 256 x 16B
#pragma unroll
    for (int i = 0; i < 15; ++i) {
        __builtin_amdgcn_global_load_lds(AS1((const short*)wp + (size_t)(i * 256 + t) * 8),
                                         AS3(Bs + (i * 256 + wv * 64) * 8), 16, 0, 0);
    }
    asm volatile("s_waitcnt vmcnt(0)" ::: "memory");
    __syncthreads();

    f32x4 acc[4][6] = {};
    const short* xbase = (const short*)xp + ((size_t)(img * XR + h) * XC + w0) * DIM;
#pragma unroll
    for (int ks = 0; ks < 5; ++ks) {
        int k0 = ks * 32 + half * 8;
        int tau = k0 >> 4, j0 = k0 & 8;
        int dy = tau / 3, dx = tau - dy * 3;
        bf16x8 af[4], bfr[6];
#pragma unroll
        for (int m = 0; m < 4; ++m) {
            int col = wr * 64 + m * 16 + m0 + dx;
            af[m] = *(const bf16x8*)(xbase + ((size_t)dy * XC + col) * DIM + j0);
        }
#pragma unroll
        for (int n = 0; n < 6; ++n) {
            int nr = wc * 96 + n * 16 + m0;
            bfr[n] = *(const bf16x8*)(Bs + ((ks * 4 + half) * HID + nr) * 8);
        }
#pragma unroll
        for (int m = 0; m < 4; ++m)
#pragma unroll
            for (int n = 0; n < 6; ++n)
                acc[m][n] = __builtin_amdgcn_mfma_f32_16x16x32_bf16(af[m], bfr[n], acc[m][n], 0, 0, 0);
    }

    // epilogue: bounce C through LDS (stride 200 shorts, 16B-aligned rows)
    __syncthreads();                    // all Bs reads complete
    short* Cs = Bs;                     // 128 x 200 shorts = 51,200 B
#pragma unroll
    for (int m = 0; m < 4; ++m)
#pragma unroll
        for (int n = 0; n < 6; ++n)
#pragma unroll
            for (int r4 = 0; r4 < 4; ++r4) {
                int prow = wr * 64 + m * 16 + half * 4 + r4;
                int chn = wc * 96 + n * 16 + m0;
                Cs[prow * 200 + chn] = f2bf(acc[m][n][r4]);
            }
    __syncthreads();
    int pix0 = (img * H + h) * W + w0;
    unsigned short* qp = (unsigned short*)qkv + (size_t)pix0 * HID;
#pragma unroll
    for (int i = 0; i < 12; ++i) {      // 128 rows x 24 granules = 3072 16B-chunks
        int s = i * 256 + t;
        int rrow = s / 24, gg = s - rrow * 24;
        s16x8 val = *(const s16x8*)(Cs + rrow * 200 + gg * 8);
        *(s16x8*)(qp + (size_t)rrow * HID + gg * 8) = val;   // fully contiguous tile
    }
}

// ---------------- K3: per-patch circular conv + LN + gate + 1x1 out conv ----------------
__global__ __launch_bounds__(256) void patch_kernel(const __hip_bfloat16* __restrict__ qkv,
                                                    const float* __restrict__ lns,
                                                    const float* __restrict__ lnb,
                                                    const float* __restrict__ wout,
                                                    float* __restrict__ out) {
    constexpr int ST = 68;                    // f32 words / ushorts per px row (16B aligned)
    __shared__ __align__(16) float smem[2 * 64 * ST];   // qs | ks ; qs reused as gs
    __shared__ __align__(16) unsigned short vsm[64 * ST];
    __shared__ float wos[64 * 16];
    __shared__ float lnSs[64], lnBs[64], meanA[64], rsigA[64];
    float* qs = smem;
    float* ks = smem + 64 * ST;

    int bid = blockIdx.x;
    int pw = bid % 48;
    int tmp = bid / 48;
    int ph = tmp % 48;
    int img = tmp / 48;
    int t = threadIdx.x, wv = t >> 6, lane = t & 63;
    int base_pix = (img * H + ph * 8) * W + pw * 8;

    // ---- stage q,k,v: ushort4 vectorized, coalesced 384B runs ----
#pragma unroll
    for (int i = 0; i < 12; ++i) {
        int idx = i * 256 + t;                // 64 px x 48 ch4-groups
        int ch4 = idx % 48, px = idx / 48;
        int pix = base_pix + (px >> 3) * W + (px & 7);
        u16x4 v4 = *(const u16x4*)((const unsigned short*)qkv + (size_t)pix * HID + ch4 * 4);
        if (ch4 < 16) {
            f32x4 f = {bf2f(v4[0]), bf2f(v4[1]), bf2f(v4[2]), bf2f(v4[3])};
            *(f32x4*)(qs + px * ST + ch4 * 4) = f;
        } else if (ch4 < 32) {
            f32x4 f = {bf2f(v4[0]), bf2f(v4[1]), bf2f(v4[2]), bf2f(v4[3])};
            *(f32x4*)(ks + px * ST + (ch4 - 16) * 4) = f;
        } else {
            *(u16x4*)(vsm + px * ST + (ch4 - 32) * 4) = v4;
        }
    }
    for (int i = t; i < 64 * 16; i += 256) wos[i] = wout[i];
    if (t < 64) { lnSs[t] = lns[t]; lnBs[t] = lnb[t]; }
    __syncthreads();

    // ---- circular conv: out[a,b] = sum_{ip,j} q[(a-ip)&7][j] * k[ip][(b-j)&7], ch = lane ----
    float acc[16];
#pragma unroll
    for (int pp = 0; pp < 16; ++pp) acc[pp] = 0.f;
#pragma unroll
    for (int ip = 0; ip < 8; ++ip) {
        float kg[8];
#pragma unroll
        for (int j = 0; j < 8; ++j) kg[j] = ks[(ip * 8 + j) * ST + lane];
        int r0 = (wv * 2 - ip) & 7;
        int r1 = (wv * 2 + 1 - ip) & 7;
        float q0[8], q1[8];
#pragma unroll
        for (int j = 0; j < 8; ++j) {
            q0[j] = qs[(r0 * 8 + j) * ST + lane];
            q1[j] = qs[(r1 * 8 + j) * ST + lane];
        }
#pragma unroll
        for (int pp = 0; pp < 16; ++pp) {
            int b = pp & 7;
#pragma unroll
            for (int j = 0; j < 8; ++j) {
                float qv = (pp < 8) ? q0[j] : q1[j];
                acc[pp] += qv * kg[(b - j) & 7];
            }
        }
    }
    __syncthreads();                          // all conv reads of qs done

    // ---- write raw conv to gs[px][ch] (reuse qs region) ----
    float* gs = qs;
#pragma unroll
    for (int pp = 0; pp < 16; ++pp) {
        int p = wv * 16 + pp;
        gs[p * ST + lane] = acc[pp];          // lanes stride-1: conflict-free
    }
    __syncthreads();

    // ---- per-pixel LN stats: 4 threads per pixel ----
    {
        int px = t >> 2, qq = t & 3;
        float s = 0.f, ss = 0.f;
#pragma unroll
        for (int u = 0; u < 16; ++u) {
            float v = gs[px * ST + qq * 16 + u];
            s += v; ss += v * v;
        }
        s  += __shfl_xor(s, 1, 64);  ss += __shfl_xor(ss, 1, 64);
        s  += __shfl_xor(s, 2, 64);  ss += __shfl_xor(ss, 2, 64);
        if (qq == 0) {
            float mean = s * (1.f / 64.f);
            float var = ss * (1.f / 64.f) - mean * mean;
            meanA[px] = mean;
            rsigA[px] = rsqrtf(var + 1e-6f);
        }
    }
    __syncthreads();

    // ---- fused LN + gate + 1x1 conv (64ch -> 16) ----
    int p = t & 63, og = t >> 6;
    float mean = meanA[p], rsig = rsigA[p];
    f32x4 o = {0.f, 0.f, 0.f, 0.f};
#pragma unroll
    for (int c4 = 0; c4 < 16; ++c4) {
        f32x4 graw = *(const f32x4*)(gs + p * ST + c4 * 4);       // b128, conflict-free
        u16x4 vv = *(const u16x4*)(vsm + p * ST + c4 * 4);        // b64, conflict-free
        f32x4 s4 = *(const f32x4*)(lnSs + c4 * 4);                // broadcast
        f32x4 b4 = *(const f32x4*)(lnBs + c4 * 4);
#pragma unroll
        for (int u = 0; u < 4; ++u) {
            int ch = c4 * 4 + u;
            float vf = bf2f((unsigned short)vv[u]);
            float g = ((graw[u] - mean) * rsig * s4[u] + b4[u]) * vf;
            f32x4 w4 = *(const f32x4*)(wos + ch * 16 + og * 4);   // broadcast
            o[0] += g * w4[0]; o[1] += g * w4[1];
            o[2] += g * w4[2]; o[3] += g * w4[3];
        }
    }
    int pix = base_pix + (p >> 3) * W + (p & 7);
    *(f32x4*)(out + (size_t)pix * 16 + og * 4) = o;
}

extern "C" void kernel_launch(void* const* d_in, const int* in_sizes, int n_in,
                              void* d_out, int out_size, void* d_ws, size_t ws_size,
                              hipStream_t stream) {
    const float* x        = (const float*)d_in[0];
    const float* w_hidden = (const float*)d_in[1];
    const float* w_qkv    = (const float*)d_in[2];
    const float* ln_scale = (const float*)d_in[3];
    const float* ln_bias  = (const float*)d_in[4];
    const float* w_out    = (const float*)d_in[5];
    float* out = (float*)d_out;

    char* wsp = (char*)d_ws;
    const size_t WP_BYTES = (size_t)KP * HID * 2;               // 61,440
    const size_t XP_BYTES = (size_t)IMG * XR * XC * DIM * 2;    // 9,585,152
    __hip_bfloat16* wp  = (__hip_bfloat16*)wsp;
    __hip_bfloat16* xp  = (__hip_bfloat16*)(wsp + 65536);
    __hip_bfloat16* qkv = (__hip_bfloat16*)(wsp + 65536 + XP_BYTES);
    (void)WP_BYTES;

    weff_pack<<<(KP * HID + 255) / 256, 256, 0, stream>>>(w_hidden, w_qkv, wp);
    xpad<<<(IMG * XR * XC + 255) / 256, 256, 0, stream>>>(x, xp);
    conv_fused<<<2304, 256, 0, stream>>>(xp, wp, qkv);
    patch_kernel<<<IMG * 48 * 48, 256, 0, stream>>>(qkv, ln_scale, ln_bias, w_out, out);
}

// Round 13
// 197.506 us; speedup vs baseline: 3.2627x; 1.0260x over previous
//
#include <hip/hip_runtime.h>
#include <hip/hip_bf16.h>

typedef short bf16x8 __attribute__((ext_vector_type(8)));
typedef short s16x8 __attribute__((ext_vector_type(8)));
typedef float f32x4 __attribute__((ext_vector_type(4)));
typedef float f32x2 __attribute__((ext_vector_type(2)));
typedef unsigned short u16x4 __attribute__((ext_vector_type(4)));

#define AS1(p) (const __attribute__((address_space(1))) void*)(p)
#define AS3(p) (__attribute__((address_space(3))) void*)(p)

constexpr int IMG = 2, H = 384, W = 384, DIM = 16, HID = 192;
constexpr int XR = 388, XC = 386;     // padded x: rows 0..387 (386,387 zero), cols 0..385
constexpr int KP = 160;               // padded K (9 taps * 16 ch = 144, pad to 160)

__device__ inline short f2bf(float v) {
    __hip_bfloat16 b = __float2bfloat16(v);
    short s; __builtin_memcpy(&s, &b, 2); return s;
}
__device__ inline float bf2f(unsigned short u) {
    return __uint_as_float((unsigned)u << 16);
}

// ---- K0: Weff[tau][j][n] = sum_c wh[j][c] * wq[tau][c][n], packed [g][n][8] bf16 ----
__global__ __launch_bounds__(256) void weff_pack(const float* __restrict__ wh,
                                                 const float* __restrict__ wq,
                                                 __hip_bfloat16* __restrict__ wp) {
    int idx = blockIdx.x * 256 + threadIdx.x;     // 160*192 = 30720
    if (idx >= KP * HID) return;
    int n = idx % HID, k = idx / HID;
    float v = 0.f;
    if (k < 144) {
        int tau = k >> 4, j = k & 15;
        const float* whp = wh + j * HID;
        const float* wqp = wq + (size_t)tau * HID * HID + n;
#pragma unroll 4
        for (int c = 0; c < HID; ++c) v += whp[c] * wqp[(size_t)c * HID];
    }
    int g = k >> 3, e = k & 7;
    wp[((size_t)g * HID + n) * 8 + e] = __float2bfloat16(v);
}

// ---- K1: pad x -> xp[2][388][386][16] bf16 (border + rows 386/387 zero) ----
__global__ __launch_bounds__(256) void xpad(const float* __restrict__ x,
                                            __hip_bfloat16* __restrict__ xp) {
    int p = blockIdx.x * 256 + threadIdx.x;
    if (p >= IMG * XR * XC) return;
    int img = p / (XR * XC), rem = p - img * (XR * XC);
    int r = rem / XC, c = rem - r * XC;
    s16x8 lo = {0,0,0,0,0,0,0,0}, hi = {0,0,0,0,0,0,0,0};
    if (r >= 1 && r <= H && c >= 1 && c <= W) {
        const float* src = x + ((size_t)(img * H + r - 1) * W + (c - 1)) * DIM;
        f32x4 a0 = *(const f32x4*)(src), a1 = *(const f32x4*)(src + 4);
        f32x4 a2 = *(const f32x4*)(src + 8), a3 = *(const f32x4*)(src + 12);
#pragma unroll
        for (int u = 0; u < 4; ++u) {
            lo[u] = f2bf(a0[u]); lo[4 + u] = f2bf(a1[u]);
            hi[u] = f2bf(a2[u]); hi[4 + u] = f2bf(a3[u]);
        }
    }
    short* dst = (short*)xp + (size_t)p * DIM;
    *(s16x8*)dst = lo;
    *(s16x8*)(dst + 8) = hi;
}

// ---- K2: qkv = conv3x3(x @ Wh) fused as x (*) Weff. M=294912, N=192, K=144(->160) ----
__global__ __launch_bounds__(256) void conv_fused(const __hip_bfloat16* __restrict__ xp,
                                                  const __hip_bfloat16* __restrict__ wp,
                                                  __hip_bfloat16* __restrict__ qkv) {
    __shared__ __align__(16) short Bs[20 * HID * 8];   // 61,440 B; reused as C-bounce
    int nb = gridDim.x;                 // 2304, divisible by 8
    int bid = blockIdx.x;
    int swz = (bid & 7) * (nb >> 3) + (bid >> 3);      // XCD-bijective swizzle
    int tw = swz % 3, row = swz / 3;
    int img = row / H, h = row - img * H;
    int w0 = tw * 128;
    int t = threadIdx.x;
    int wv = t >> 6, lane = t & 63;
    int wr = wv >> 1, wc = wv & 1;
    int m0 = lane & 15, half = lane >> 4;

    // stage Weff^T (linear copy: source layout == LDS layout): 15 x 256 x 16B
#pragma unroll
    for (int i = 0; i < 15; ++i) {
        __builtin_amdgcn_global_load_lds(AS1((const short*)wp + (size_t)(i * 256 + t) * 8),
                                         AS3(Bs + (i * 256 + wv * 64) * 8), 16, 0, 0);
    }
    asm volatile("s_waitcnt vmcnt(0)" ::: "memory");
    __syncthreads();

    f32x4 acc[4][6] = {};
    const short* xbase = (const short*)xp + ((size_t)(img * XR + h) * XC + w0) * DIM;
#pragma unroll
    for (int ks = 0; ks < 5; ++ks) {
        int k0 = ks * 32 + half * 8;
        int tau = k0 >> 4, j0 = k0 & 8;
        int dy = tau / 3, dx = tau - dy * 3;
        bf16x8 af[4], bfr[6];
#pragma unroll
        for (int m = 0; m < 4; ++m) {
            int col = wr * 64 + m * 16 + m0 + dx;
            af[m] = *(const bf16x8*)(xbase + ((size_t)dy * XC + col) * DIM + j0);
        }
#pragma unroll
        for (int n = 0; n < 6; ++n) {
            int nr = wc * 96 + n * 16 + m0;
            bfr[n] = *(const bf16x8*)(Bs + ((ks * 4 + half) * HID + nr) * 8);
        }
#pragma unroll
        for (int m = 0; m < 4; ++m)
#pragma unroll
            for (int n = 0; n < 6; ++n)
                acc[m][n] = __builtin_amdgcn_mfma_f32_16x16x32_bf16(af[m], bfr[n], acc[m][n], 0, 0, 0);
    }

    // epilogue: bounce C through LDS (stride 200 shorts, 16B-aligned rows)
    __syncthreads();                    // all Bs reads complete
    short* Cs = Bs;                     // 128 x 200 shorts = 51,200 B
#pragma unroll
    for (int m = 0; m < 4; ++m)
#pragma unroll
        for (int n = 0; n < 6; ++n)
#pragma unroll
            for (int r4 = 0; r4 < 4; ++r4) {
                int prow = wr * 64 + m * 16 + half * 4 + r4;
                int chn = wc * 96 + n * 16 + m0;
                Cs[prow * 200 + chn] = f2bf(acc[m][n][r4]);
            }
    __syncthreads();
    int pix0 = (img * H + h) * W + w0;
    unsigned short* qp = (unsigned short*)qkv + (size_t)pix0 * HID;
#pragma unroll
    for (int i = 0; i < 12; ++i) {      // 128 rows x 24 granules = 3072 16B-chunks
        int s = i * 256 + t;
        int rrow = s / 24, gg = s - rrow * 24;
        s16x8 val = *(const s16x8*)(Cs + rrow * 200 + gg * 8);
        *(s16x8*)(qp + (size_t)rrow * HID + gg * 8) = val;   // fully contiguous tile
    }
}

// ---------------- K3: per-patch circular conv + LN + gate + 1x1 out conv ----------------
// v_pk_fma_f32 pairing: acc[pp] and acc[pp+8] share kg broadcast, differ in q-row.
__global__ __launch_bounds__(256) void patch_kernel(const __hip_bfloat16* __restrict__ qkv,
                                                    const float* __restrict__ lns,
                                                    const float* __restrict__ lnb,
                                                    const float* __restrict__ wout,
                                                    float* __restrict__ out) {
    constexpr int ST = 68;                    // f32 words / ushorts per px row (16B aligned)
    __shared__ __align__(16) float smem[2 * 64 * ST];   // qs | ks ; qs reused as gs
    __shared__ __align__(16) unsigned short vsm[64 * ST];
    __shared__ float wos[64 * 16];
    __shared__ float lnSs[64], lnBs[64], meanA[64], rsigA[64];
    float* qs = smem;
    float* ks = smem + 64 * ST;

    int bid = blockIdx.x;
    int pw = bid % 48;
    int tmp = bid / 48;
    int ph = tmp % 48;
    int img = tmp / 48;
    int t = threadIdx.x, wv = t >> 6, lane = t & 63;
    int base_pix = (img * H + ph * 8) * W + pw * 8;

    // ---- stage q,k,v: ushort4 vectorized, coalesced 384B runs ----
#pragma unroll
    for (int i = 0; i < 12; ++i) {
        int idx = i * 256 + t;                // 64 px x 48 ch4-groups
        int ch4 = idx % 48, px = idx / 48;
        int pix = base_pix + (px >> 3) * W + (px & 7);
        u16x4 v4 = *(const u16x4*)((const unsigned short*)qkv + (size_t)pix * HID + ch4 * 4);
        if (ch4 < 16) {
            f32x4 f = {bf2f(v4[0]), bf2f(v4[1]), bf2f(v4[2]), bf2f(v4[3])};
            *(f32x4*)(qs + px * ST + ch4 * 4) = f;
        } else if (ch4 < 32) {
            f32x4 f = {bf2f(v4[0]), bf2f(v4[1]), bf2f(v4[2]), bf2f(v4[3])};
            *(f32x4*)(ks + px * ST + (ch4 - 16) * 4) = f;
        } else {
            *(u16x4*)(vsm + px * ST + (ch4 - 32) * 4) = v4;
        }
    }
    for (int i = t; i < 64 * 16; i += 256) wos[i] = wout[i];
    if (t < 64) { lnSs[t] = lns[t]; lnBs[t] = lnb[t]; }
    __syncthreads();

    // ---- circular conv, packed pairs: acc2[b] = {out[wv*2 rowpair? no: pp, pp+8]} ----
    // out[a,b] = sum_{ip,j} q[(a-ip)&7][j] * k[ip][(b-j)&7]; a = wv*2 + (pp<8?0:1)
    f32x2 acc2[8];
#pragma unroll
    for (int b = 0; b < 8; ++b) acc2[b] = {0.f, 0.f};
#pragma unroll
    for (int ip = 0; ip < 8; ++ip) {
        float kg[8];
#pragma unroll
        for (int j = 0; j < 8; ++j) kg[j] = ks[(ip * 8 + j) * ST + lane];
        int r0 = (wv * 2 - ip) & 7;
        int r1 = (wv * 2 + 1 - ip) & 7;
        f32x2 q2[8];
#pragma unroll
        for (int j = 0; j < 8; ++j)
            q2[j] = {qs[(r0 * 8 + j) * ST + lane], qs[(r1 * 8 + j) * ST + lane]};
#pragma unroll
        for (int b = 0; b < 8; ++b) {
#pragma unroll
            for (int j = 0; j < 8; ++j) {
                float kv = kg[(b - j) & 7];
                f32x2 k2 = {kv, kv};
                acc2[b] += q2[j] * k2;         // v_pk_fma_f32
            }
        }
    }
    __syncthreads();                          // all conv reads of qs done

    // ---- write raw conv to gs[px][ch] (reuse qs region) ----
    float* gs = qs;
#pragma unroll
    for (int b = 0; b < 8; ++b) {
        gs[(wv * 16 + b) * ST + lane] = acc2[b][0];
        gs[(wv * 16 + 8 + b) * ST + lane] = acc2[b][1];
    }
    __syncthreads();

    // ---- per-pixel LN stats: 4 threads per pixel, vector loads ----
    {
        int px = t >> 2, qq = t & 3;
        const float* gp = gs + px * ST + qq * 16;
        f32x4 v0 = *(const f32x4*)(gp);
        f32x4 v1 = *(const f32x4*)(gp + 4);
        f32x4 v2 = *(const f32x4*)(gp + 8);
        f32x4 v3 = *(const f32x4*)(gp + 12);
        f32x4 sv = v0 + v1 + v2 + v3;
        f32x4 ssv = v0 * v0 + v1 * v1 + v2 * v2 + v3 * v3;
        float s = sv[0] + sv[1] + sv[2] + sv[3];
        float ss = ssv[0] + ssv[1] + ssv[2] + ssv[3];
        s  += __shfl_xor(s, 1, 64);  ss += __shfl_xor(ss, 1, 64);
        s  += __shfl_xor(s, 2, 64);  ss += __shfl_xor(ss, 2, 64);
        if (qq == 0) {
            float mean = s * (1.f / 64.f);
            float var = ss * (1.f / 64.f) - mean * mean;
            meanA[px] = mean;
            rsigA[px] = rsqrtf(var + 1e-6f);
        }
    }
    __syncthreads();

    // ---- fused LN + gate + 1x1 conv (64ch -> 16), vectorized accumulate ----
    int p = t & 63, og = t >> 6;
    float mean = meanA[p], rsig = rsigA[p];
    f32x4 o = {0.f, 0.f, 0.f, 0.f};
#pragma unroll
    for (int c4 = 0; c4 < 16; ++c4) {
        f32x4 graw = *(const f32x4*)(gs + p * ST + c4 * 4);       // b128, conflict-free
        u16x4 vv = *(const u16x4*)(vsm + p * ST + c4 * 4);        // b64, conflict-free
        f32x4 s4 = *(const f32x4*)(lnSs + c4 * 4);                // broadcast
        f32x4 b4 = *(const f32x4*)(lnBs + c4 * 4);
#pragma unroll
        for (int u = 0; u < 4; ++u) {
            int ch = c4 * 4 + u;
            float vf = bf2f((unsigned short)vv[u]);
            float g = ((graw[u] - mean) * rsig * s4[u] + b4[u]) * vf;
            f32x4 g4 = {g, g, g, g};
            f32x4 w4 = *(const f32x4*)(wos + ch * 16 + og * 4);   // broadcast
            o += g4 * w4;                                          // 2x v_pk_fma_f32
        }
    }
    int pix = base_pix + (p >> 3) * W + (p & 7);
    *(f32x4*)(out + (size_t)pix * 16 + og * 4) = o;
}

extern "C" void kernel_launch(void* const* d_in, const int* in_sizes, int n_in,
                              void* d_out, int out_size, void* d_ws, size_t ws_size,
                              hipStream_t stream) {
    const float* x        = (const float*)d_in[0];
    const float* w_hidden = (const float*)d_in[1];
    const float* w_qkv    = (const float*)d_in[2];
    const float* ln_scale = (const float*)d_in[3];
    const float* ln_bias  = (const float*)d_in[4];
    const float* w_out    = (const float*)d_in[5];
    float* out = (float*)d_out;

    char* wsp = (char*)d_ws;
    const size_t XP_BYTES = (size_t)IMG * XR * XC * DIM * 2;    // 9,585,152
    __hip_bfloat16* wp  = (__hip_bfloat16*)wsp;
    __hip_bfloat16* xp  = (__hip_bfloat16*)(wsp + 65536);
    __hip_bfloat16* qkv = (__hip_bfloat16*)(wsp + 65536 + XP_BYTES);

    weff_pack<<<(KP * HID + 255) / 256, 256, 0, stream>>>(w_hidden, w_qkv, wp);
    xpad<<<(IMG * XR * XC + 255) / 256, 256, 0, stream>>>(x, xp);
    conv_fused<<<2304, 256, 0, stream>>>(xp, wp, qkv);
    patch_kernel<<<IMG * 48 * 48, 256, 0, stream>>>(qkv, ln_scale, ln_bias, w_out, out);
}

// Round 14
// 181.336 us; speedup vs baseline: 3.5536x; 1.0892x over previous
//
#include <hip/hip_runtime.h>
#include <hip/hip_bf16.h>

typedef short bf16x8 __attribute__((ext_vector_type(8)));
typedef short s16x8 __attribute__((ext_vector_type(8)));
typedef float f32x4 __attribute__((ext_vector_type(4)));
typedef float f32x2 __attribute__((ext_vector_type(2)));
typedef unsigned short u16x4 __attribute__((ext_vector_type(4)));

#define AS1(p) (const __attribute__((address_space(1))) void*)(p)
#define AS3(p) (__attribute__((address_space(3))) void*)(p)

constexpr int IMG = 2, H = 384, W = 384, DIM = 16, HID = 192;
constexpr int XR = 388, XC = 386;     // padded x: rows 0..387 (386,387 zero), cols 0..385
constexpr int KP = 160;               // padded K (9 taps * 16 ch = 144, pad to 160)

__device__ inline short f2bf(float v) {
    __hip_bfloat16 b = __float2bfloat16(v);
    short s; __builtin_memcpy(&s, &b, 2); return s;
}
__device__ inline float bf2f(unsigned short u) {
    return __uint_as_float((unsigned)u << 16);
}

// ---- K0: Weff[tau][j][n] = sum_c wh[j][c] * wq[tau][c][n], packed [g][n][8] bf16 ----
__global__ __launch_bounds__(256) void weff_pack(const float* __restrict__ wh,
                                                 const float* __restrict__ wq,
                                                 __hip_bfloat16* __restrict__ wp) {
    int idx = blockIdx.x * 256 + threadIdx.x;     // 160*192 = 30720
    if (idx >= KP * HID) return;
    int n = idx % HID, k = idx / HID;
    float v = 0.f;
    if (k < 144) {
        int tau = k >> 4, j = k & 15;
        const float* whp = wh + j * HID;
        const float* wqp = wq + (size_t)tau * HID * HID + n;
#pragma unroll 4
        for (int c = 0; c < HID; ++c) v += whp[c] * wqp[(size_t)c * HID];
    }
    int g = k >> 3, e = k & 7;
    wp[((size_t)g * HID + n) * 8 + e] = __float2bfloat16(v);
}

// ---- K1: pad x -> xp[2][388][386][16] bf16 (border + rows 386/387 zero) ----
__global__ __launch_bounds__(256) void xpad(const float* __restrict__ x,
                                            __hip_bfloat16* __restrict__ xp) {
    int p = blockIdx.x * 256 + threadIdx.x;
    if (p >= IMG * XR * XC) return;
    int img = p / (XR * XC), rem = p - img * (XR * XC);
    int r = rem / XC, c = rem - r * XC;
    s16x8 lo = {0,0,0,0,0,0,0,0}, hi = {0,0,0,0,0,0,0,0};
    if (r >= 1 && r <= H && c >= 1 && c <= W) {
        const float* src = x + ((size_t)(img * H + r - 1) * W + (c - 1)) * DIM;
        f32x4 a0 = *(const f32x4*)(src), a1 = *(const f32x4*)(src + 4);
        f32x4 a2 = *(const f32x4*)(src + 8), a3 = *(const f32x4*)(src + 12);
#pragma unroll
        for (int u = 0; u < 4; ++u) {
            lo[u] = f2bf(a0[u]); lo[4 + u] = f2bf(a1[u]);
            hi[u] = f2bf(a2[u]); hi[4 + u] = f2bf(a3[u]);
        }
    }
    short* dst = (short*)xp + (size_t)p * DIM;
    *(s16x8*)dst = lo;
    *(s16x8*)(dst + 8) = hi;
}

// ---- K2: qkv = conv3x3(x @ Wh) fused as x (*) Weff. M=294912, N=192, K=144(->160) ----
__global__ __launch_bounds__(256) void conv_fused(const __hip_bfloat16* __restrict__ xp,
                                                  const __hip_bfloat16* __restrict__ wp,
                                                  __hip_bfloat16* __restrict__ qkv) {
    __shared__ __align__(16) short Bs[20 * HID * 8];   // 61,440 B; reused as C-bounce
    int nb = gridDim.x;                 // 2304, divisible by 8
    int bid = blockIdx.x;
    int swz = (bid & 7) * (nb >> 3) + (bid >> 3);      // XCD-bijective swizzle
    int tw = swz % 3, row = swz / 3;
    int img = row / H, h = row - img * H;
    int w0 = tw * 128;
    int t = threadIdx.x;
    int wv = t >> 6, lane = t & 63;
    int wr = wv >> 1, wc = wv & 1;
    int m0 = lane & 15, half = lane >> 4;

    // stage Weff^T (linear copy: source layout == LDS layout): 15 x 256 x 16B
#pragma unroll
    for (int i = 0; i < 15; ++i) {
        __builtin_amdgcn_global_load_lds(AS1((const short*)wp + (size_t)(i * 256 + t) * 8),
                                         AS3(Bs + (i * 256 + wv * 64) * 8), 16, 0, 0);
    }
    asm volatile("s_waitcnt vmcnt(0)" ::: "memory");
    __syncthreads();

    f32x4 acc[4][6] = {};
    const short* xbase = (const short*)xp + ((size_t)(img * XR + h) * XC + w0) * DIM;
#pragma unroll
    for (int ks = 0; ks < 5; ++ks) {
        int k0 = ks * 32 + half * 8;
        int tau = k0 >> 4, j0 = k0 & 8;
        int dy = tau / 3, dx = tau - dy * 3;
        bf16x8 af[4], bfr[6];
#pragma unroll
        for (int m = 0; m < 4; ++m) {
            int col = wr * 64 + m * 16 + m0 + dx;
            af[m] = *(const bf16x8*)(xbase + ((size_t)dy * XC + col) * DIM + j0);
        }
#pragma unroll
        for (int n = 0; n < 6; ++n) {
            int nr = wc * 96 + n * 16 + m0;
            bfr[n] = *(const bf16x8*)(Bs + ((ks * 4 + half) * HID + nr) * 8);
        }
#pragma unroll
        for (int m = 0; m < 4; ++m)
#pragma unroll
            for (int n = 0; n < 6; ++n)
                acc[m][n] = __builtin_amdgcn_mfma_f32_16x16x32_bf16(af[m], bfr[n], acc[m][n], 0, 0, 0);
    }

    // epilogue: bounce C through LDS (stride 200 shorts, 16B-aligned rows)
    __syncthreads();                    // all Bs reads complete
    short* Cs = Bs;                     // 128 x 200 shorts = 51,200 B
#pragma unroll
    for (int m = 0; m < 4; ++m)
#pragma unroll
        for (int n = 0; n < 6; ++n)
#pragma unroll
            for (int r4 = 0; r4 < 4; ++r4) {
                int prow = wr * 64 + m * 16 + half * 4 + r4;
                int chn = wc * 96 + n * 16 + m0;
                Cs[prow * 200 + chn] = f2bf(acc[m][n][r4]);
            }
    __syncthreads();
    int pix0 = (img * H + h) * W + w0;
    unsigned short* qp = (unsigned short*)qkv + (size_t)pix0 * HID;
#pragma unroll
    for (int i = 0; i < 12; ++i) {      // 128 rows x 24 granules = 3072 16B-chunks
        int s = i * 256 + t;
        int rrow = s / 24, gg = s - rrow * 24;
        s16x8 val = *(const s16x8*)(Cs + rrow * 200 + gg * 8);
        *(s16x8*)(qp + (size_t)rrow * HID + gg * 8) = val;   // fully contiguous tile
    }
}

// ---------------- K3: per-patch circular conv + LN + gate + 1x1 out conv ----------------
// bf16 LDS staging (q/k raw u16, 18.4 KB) + no wos LDS -> 27.5 KB total -> 5 blocks/CU.
__global__ __launch_bounds__(256) void patch_kernel(const __hip_bfloat16* __restrict__ qkv,
                                                    const float* __restrict__ lns,
                                                    const float* __restrict__ lnb,
                                                    const float* __restrict__ wout,
                                                    float* __restrict__ out) {
    constexpr int QST = 72;                   // q/k row stride in shorts (144B)
    constexpr int VST = 68;                   // v row stride in shorts (136B)
    constexpr int GST = 68;                   // gs row stride in floats (272B)
    __shared__ __align__(16) unsigned char raw[64 * QST * 2 * 2 + 64 * VST * 2 + 4 * 256];
    unsigned short* qsu = (unsigned short*)raw;                 // [64px][72]
    unsigned short* ksu = qsu + 64 * QST;                       // [64px][72]
    unsigned short* vsu = (unsigned short*)(raw + 64 * QST * 4);// [64px][68]
    float* gs = (float*)raw;                                    // overlay q/k after conv
    float* meanA = (float*)(raw + 64 * QST * 4 + 64 * VST * 2);
    float* rsigA = meanA + 64;
    float* lnSs = rsigA + 64;
    float* lnBs = lnSs + 64;

    int bid = blockIdx.x;
    int pw = bid % 48;
    int tmp = bid / 48;
    int ph = tmp % 48;
    int img = tmp / 48;
    int t = threadIdx.x, wv = t >> 6, lane = t & 63;
    int base_pix = (img * H + ph * 8) * W + pw * 8;

    // ---- stage q,k,v as raw bf16 (u16x4 = b64 writes, conflict-free) ----
#pragma unroll
    for (int i = 0; i < 12; ++i) {
        int idx = i * 256 + t;                // 64 px x 48 ch4-groups
        int ch4 = idx % 48, px = idx / 48;
        int pix = base_pix + (px >> 3) * W + (px & 7);
        u16x4 v4 = *(const u16x4*)((const unsigned short*)qkv + (size_t)pix * HID + ch4 * 4);
        if (ch4 < 16) {
            *(u16x4*)(qsu + px * QST + ch4 * 4) = v4;
        } else if (ch4 < 32) {
            *(u16x4*)(ksu + px * QST + (ch4 - 16) * 4) = v4;
        } else {
            *(u16x4*)(vsu + px * VST + (ch4 - 32) * 4) = v4;
        }
    }
    if (t < 64) { lnSs[t] = lns[t]; lnBs[t] = lnb[t]; }
    __syncthreads();

    // ---- circular conv, packed row-pairs: out[a,b], a = wv*2 + slot ----
    f32x2 acc2[8];
#pragma unroll
    for (int b = 0; b < 8; ++b) acc2[b] = {0.f, 0.f};
#pragma unroll
    for (int ip = 0; ip < 8; ++ip) {
        float kg[8];
#pragma unroll
        for (int j = 0; j < 8; ++j) kg[j] = bf2f(ksu[(ip * 8 + j) * QST + lane]);
        int r0 = (wv * 2 - ip) & 7;
        int r1 = (wv * 2 + 1 - ip) & 7;
        f32x2 q2[8];
#pragma unroll
        for (int j = 0; j < 8; ++j)
            q2[j] = {bf2f(qsu[(r0 * 8 + j) * QST + lane]),
                     bf2f(qsu[(r1 * 8 + j) * QST + lane])};
#pragma unroll
        for (int b = 0; b < 8; ++b) {
#pragma unroll
            for (int j = 0; j < 8; ++j) {
                float kv = kg[(b - j) & 7];
                f32x2 k2 = {kv, kv};
                acc2[b] += q2[j] * k2;         // v_pk_fma_f32
            }
        }
    }
    __syncthreads();                          // all conv reads of qsu/ksu done

    // ---- write raw conv to gs[px][ch] f32 (overlays q/k region) ----
#pragma unroll
    for (int b = 0; b < 8; ++b) {
        gs[(wv * 16 + b) * GST + lane] = acc2[b][0];
        gs[(wv * 16 + 8 + b) * GST + lane] = acc2[b][1];
    }
    __syncthreads();

    // ---- per-pixel LN stats: 4 threads per pixel, vector loads ----
    {
        int px = t >> 2, qq = t & 3;
        const float* gp = gs + px * GST + qq * 16;
        f32x4 v0 = *(const f32x4*)(gp);
        f32x4 v1 = *(const f32x4*)(gp + 4);
        f32x4 v2 = *(const f32x4*)(gp + 8);
        f32x4 v3 = *(const f32x4*)(gp + 12);
        f32x4 sv = v0 + v1 + v2 + v3;
        f32x4 ssv = v0 * v0 + v1 * v1 + v2 * v2 + v3 * v3;
        float s = sv[0] + sv[1] + sv[2] + sv[3];
        float ss = ssv[0] + ssv[1] + ssv[2] + ssv[3];
        s  += __shfl_xor(s, 1, 64);  ss += __shfl_xor(ss, 1, 64);
        s  += __shfl_xor(s, 2, 64);  ss += __shfl_xor(ss, 2, 64);
        if (qq == 0) {
            float mean = s * (1.f / 64.f);
            float var = ss * (1.f / 64.f) - mean * mean;
            meanA[px] = mean;
            rsigA[px] = rsqrtf(var + 1e-6f);
        }
    }
    __syncthreads();

    // ---- fused LN + gate + 1x1 conv (64ch -> 16); w_out via wave-uniform global reads ----
    int p = t & 63, og = t >> 6;
    float mean = meanA[p], rsig = rsigA[p];
    f32x4 o = {0.f, 0.f, 0.f, 0.f};
#pragma unroll
    for (int c4 = 0; c4 < 16; ++c4) {
        f32x4 graw = *(const f32x4*)(gs + p * GST + c4 * 4);      // b128, conflict-free
        u16x4 vv = *(const u16x4*)(vsu + p * VST + c4 * 4);       // b64
        f32x4 s4 = *(const f32x4*)(lnSs + c4 * 4);                // broadcast
        f32x4 b4 = *(const f32x4*)(lnBs + c4 * 4);
#pragma unroll
        for (int u = 0; u < 4; ++u) {
            int ch = c4 * 4 + u;
            float vf = bf2f((unsigned short)vv[u]);
            float g = ((graw[u] - mean) * rsig * s4[u] + b4[u]) * vf;
            f32x4 g4 = {g, g, g, g};
            f32x4 w4 = *(const f32x4*)(wout + ch * 16 + og * 4);  // wave-uniform (s_load)
            o += g4 * w4;                                          // v_pk_fma_f32
        }
    }
    int pix = base_pix + (p >> 3) * W + (p & 7);
    *(f32x4*)(out + (size_t)pix * 16 + og * 4) = o;
}

extern "C" void kernel_launch(void* const* d_in, const int* in_sizes, int n_in,
                              void* d_out, int out_size, void* d_ws, size_t ws_size,
                              hipStream_t stream) {
    const float* x        = (const float*)d_in[0];
    const float* w_hidden = (const float*)d_in[1];
    const float* w_qkv    = (const float*)d_in[2];
    const float* ln_scale = (const float*)d_in[3];
    const float* ln_bias  = (const float*)d_in[4];
    const float* w_out    = (const float*)d_in[5];
    float* out = (float*)d_out;

    char* wsp = (char*)d_ws;
    const size_t XP_BYTES = (size_t)IMG * XR * XC * DIM * 2;    // 9,585,152
    __hip_bfloat16* wp  = (__hip_bfloat16*)wsp;
    __hip_bfloat16* xp  = (__hip_bfloat16*)(wsp + 65536);
    __hip_bfloat16* qkv = (__hip_bfloat16*)(wsp + 65536 + XP_BYTES);

    weff_pack<<<(KP * HID + 255) / 256, 256, 0, stream>>>(w_hidden, w_qkv, wp);
    xpad<<<(IMG * XR * XC + 255) / 256, 256, 0, stream>>>(x, xp);
    conv_fused<<<2304, 256, 0, stream>>>(xp, wp, qkv);
    patch_kernel<<<IMG * 48 * 48, 256, 0, stream>>>(qkv, ln_scale, ln_bias, w_out, out);
}